// Round 14
// baseline (1344.673 us; speedup 1.0000x reference)
//
#include <hip/hip_runtime.h>
#include <math.h>

#define BB 64
#define EE 512
#define HH 1024
#define VV 30000
#define TT 20
#define NBT 469
#define PSTRIDE 512

typedef __attribute__((ext_vector_type(8))) short bf16x8;
typedef __attribute__((ext_vector_type(4))) float f32x4;

// ---- ws byte offsets ----
#define OFF_W1  ((size_t)0)
#define OFF_W2  ((size_t)33554432)
#define OFF_WO  ((size_t)67108864)
#define OFF_X1  ((size_t)190054400)
#define OFF_H1  ((size_t)190316544)   // + bank*262144
#define OFF_H2  ((size_t)190840832)   // + bank*262144
#define OFF_C1  ((size_t)191365120)
#define OFF_C2  ((size_t)191627264)
#define OFF_P   ((size_t)191889408)   // 8 MB: [kq 0..7][4096][64] f32
#define OFF_PM  ((size_t)200278016)
#define OFF_PS  ((size_t)200409088)
#define OFF_PA  ((size_t)200540160)
#define OFF_LSE ((size_t)200671232)   // [20][64] f32
#define OFF_BS  ((size_t)200676352)   // 8192 f32
#define OFF_GX  ((size_t)200709120)   // 64*4096 f32 = 1MB

__device__ __forceinline__ unsigned short bf_hi(float x) {
    unsigned u = __float_as_uint(x);
    return (unsigned short)((u + 0x7fffu + ((u >> 16) & 1u)) >> 16);
}
__device__ __forceinline__ float bf_f(unsigned short h) {
    return __uint_as_float(((unsigned)h) << 16);
}
__device__ __forceinline__ void merge3(float& m, float& s, int& a,
                                       float m2, float s2, int a2) {
    if (m2 > m) { s = s * expf(m - m2) + s2; m = m2; a = a2; }
    else if (m2 == m) { s += s2; if (a2 < a) a = a2; }
    else { s += s2 * expf(m2 - m); }
}
__device__ __forceinline__ void gl16(const void* g, void* l) {
    __builtin_amdgcn_global_load_lds(
        (const unsigned int __attribute__((address_space(1)))*)g,
        (unsigned int __attribute__((address_space(3)))*)l, 16, 0, 0);
}
__device__ __forceinline__ void cvt8(const float* src, uint4& hv, uint4& lv) {
    unsigned h[8], q[8];
    #pragma unroll
    for (int i = 0; i < 8; ++i) {
        float x = src[i];
        unsigned short hi = bf_hi(x);
        unsigned short lo = bf_hi(x - bf_f(hi));
        h[i] = hi; q[i] = lo;
    }
    hv.x = h[0] | (h[1] << 16); hv.y = h[2] | (h[3] << 16);
    hv.z = h[4] | (h[5] << 16); hv.w = h[6] | (h[7] << 16);
    lv.x = q[0] | (q[1] << 16); lv.y = q[2] | (q[3] << 16);
    lv.z = q[4] | (q[5] << 16); lv.w = q[6] | (q[7] << 16);
}

// ---------------- one-time weight conversion into chunk layout ----------------
__global__ __launch_bounds__(256) void k_conv_cell(
    const float* __restrict__ Wih1, const float* __restrict__ Whh1,
    const float* __restrict__ Wih2, const float* __restrict__ Whh2, char* wsb) {
    int cell = blockIdx.y;
    const float* Wih = cell ? Wih2 : Wih1;
    const float* Whh = cell ? Whh2 : Whh1;
    char* dst = wsb + (cell ? OFF_W2 : OFF_W1);
    unsigned flat = blockIdx.x * 256 + threadIdx.x;  // < 64*32*512
    unsigned c = flat & 511, kt = (flat >> 9) & 31, rt = flat >> 14;
    unsigned s = c >> 8, bg = (c >> 6) & 3, g = (c >> 4) & 3, n = c & 15;
    unsigned row = bg * 1024 + rt * 16 + n;
    unsigned col = (kt & 15) * 64 + s * 32 + g * 8;
    const float* src = (kt < 16 ? Wih : Whh) + (size_t)row * 1024 + col;
    uint4 hv, lv; cvt8(src, hv, lv);
    char* d = dst + (size_t)rt * 524288 + kt * 16384 + c * 16;
    *(uint4*)d = hv;
    *(uint4*)(d + 8192) = lv;
}

__global__ __launch_bounds__(256) void k_conv_out(const float* __restrict__ Wout,
                                                  char* wsb) {
    unsigned flat = blockIdx.x * 256 + threadIdx.x;  // < 469*16*512
    unsigned c = flat & 511, kt = (flat >> 9) & 15, rt = flat >> 13;
    unsigned s = c >> 8, bg = (c >> 6) & 3, g = (c >> 4) & 3, n = c & 15;
    unsigned row = rt * 64 + bg * 16 + n; if (row > VV - 1) row = VV - 1;
    unsigned col = kt * 64 + s * 32 + g * 8;
    const float* src = Wout + (size_t)row * 1024 + col;
    uint4 hv, lv; cvt8(src, hv, lv);
    char* d = wsb + OFF_WO + (size_t)rt * 262144 + kt * 16384 + c * 16;
    *(uint4*)d = hv;
    *(uint4*)(d + 8192) = lv;
}

__global__ __launch_bounds__(256) void k_conv_img(const float* __restrict__ img,
                                                  char* wsb) {
    unsigned flat = blockIdx.x * 256 + threadIdx.x;  // < 8*512
    unsigned c = flat & 511, kt = flat >> 9;
    unsigned s = c >> 8, bg = (c >> 6) & 3, g = (c >> 4) & 3, n = c & 15;
    unsigned b = bg * 16 + n;
    unsigned col = kt * 64 + s * 32 + g * 8;
    const float* src = img + (size_t)b * 512 + col;
    uint4 hv, lv; cvt8(src, hv, lv);
    char* d = wsb + OFF_X1 + kt * 16384 + c * 16;
    *(uint4*)d = hv;
    *(uint4*)(d + 8192) = lv;
}

// ---------------- prep: zeros + bias sums ----------------
__global__ void k_prep(char* wsb,
                       const float* __restrict__ bih1, const float* __restrict__ bhh1,
                       const float* __restrict__ bih2, const float* __restrict__ bhh2) {
    unsigned idx = blockIdx.x * 256 + threadIdx.x;
    if (idx < 131072) { ((unsigned*)(wsb + OFF_C1))[idx] = 0u; return; }   // c1,c2
    idx -= 131072;
    if (idx < 65536) { ((unsigned*)(wsb + OFF_H1))[idx] = 0u; return; }    // H1 bank0
    idx -= 65536;
    if (idx < 65536) { ((unsigned*)(wsb + OFF_H2))[idx] = 0u; return; }    // H2 bank0
    idx -= 65536;
    if (idx < 32768) { ((unsigned*)(wsb + OFF_X1 + 131072))[idx] = 0u; return; } // X1 emb
    idx -= 32768;
    if (idx < 8192) {
        float v = (idx < 4096) ? bih1[idx] + bhh1[idx]
                               : bih2[idx - 4096] + bhh2[idx - 4096];
        ((float*)(wsb + OFF_BS))[idx] = v;
    }
}

// ---------------- emb writer ----------------
__device__ __forceinline__ void emb_write(char* X1, const float* Wemb, int tk,
                                          int b, int tid) {
    #pragma unroll
    for (int i = 0; i < 2; ++i) {
        int e = tid + i * 256;
        float x = Wemb[(size_t)tk * 512 + e];
        unsigned short hi = bf_hi(x);
        unsigned short lo = bf_hi(x - bf_f(hi));
        int k = 512 + e;
        int kt = k >> 6, kl = k & 63;
        int s = kl >> 5, gq = (kl >> 3) & 3, off = kl & 7;
        int chunk = s * 256 + (b >> 4) * 64 + gq * 16 + (b & 15);
        char* d = X1 + kt * 16384 + chunk * 16 + off * 2;
        *(unsigned short*)d = hi;
        *(unsigned short*)(d + 8192) = lo;
    }
}

__global__ void k_emb0(const float* __restrict__ Wemb, char* wsb) {
    emb_write(wsb + OFF_X1, Wemb, 1, blockIdx.x, threadIdx.x);  // START=1
}

// ------- gemm core: 64 rows x 64 b; NKT k-tiles of 64 (2x32KB LDS dbuf) -----
// A source for k-tile kt: global index ta = ktbase+kt; ta<HALF -> A0 else A1.
template <int NKT>
__device__ __forceinline__ void gemm_core(const char* __restrict__ Wsrc,
                                          const char* __restrict__ A0,
                                          const char* __restrict__ A1,
                                          int ktbase, int HALF,
                                          char* smem, int tid, f32x4 acc[4]) {
    const int l = tid & 63, w = tid >> 6, g = l >> 4, n = l & 15;
    auto stage = [&](int kt, char* buf) {
        const char* wsp = Wsrc + kt * 16384;
        int ta = ktbase + kt;
        const char* asp = (ta < HALF) ? (A0 + ta * 16384)
                                      : (A1 + (ta - HALF) * 16384);
        int o = tid * 16;
        gl16(wsp + o, buf + o);
        gl16(wsp + 4096 + o, buf + 4096 + o);
        gl16(wsp + 8192 + o, buf + 8192 + o);
        gl16(wsp + 12288 + o, buf + 12288 + o);
        gl16(asp + o, buf + 16384 + o);
        gl16(asp + 4096 + o, buf + 20480 + o);
        gl16(asp + 8192 + o, buf + 24576 + o);
        gl16(asp + 12288 + o, buf + 28672 + o);
    };
    stage(0, smem);
    __syncthreads();
    for (int kt = 0; kt < NKT; ++kt) {
        char* buf = smem + (kt & 1) * 32768;
        if (kt + 1 < NKT) stage(kt + 1, smem + ((kt + 1) & 1) * 32768);
        #pragma unroll
        for (int s = 0; s < 2; ++s) {
            int wc = (s * 256 + w * 64 + g * 16 + n) * 16;
            bf16x8 ah = *(const bf16x8*)(buf + wc);
            bf16x8 al = *(const bf16x8*)(buf + 8192 + wc);
            #pragma unroll
            for (int bg = 0; bg < 4; ++bg) {
                int ac = (s * 256 + bg * 64 + g * 16 + n) * 16;
                bf16x8 bh = *(const bf16x8*)(buf + 16384 + ac);
                bf16x8 bl = *(const bf16x8*)(buf + 24576 + ac);
                acc[bg] = __builtin_amdgcn_mfma_f32_16x16x32_bf16(ah, bh, acc[bg], 0, 0, 0);
                acc[bg] = __builtin_amdgcn_mfma_f32_16x16x32_bf16(ah, bl, acc[bg], 0, 0, 0);
                acc[bg] = __builtin_amdgcn_mfma_f32_16x16x32_bf16(al, bh, acc[bg], 0, 0, 0);
            }
        }
        __syncthreads();
    }
}

// ---------------- GX1 = Wih1[:, :512] @ img^T + bias1 (once) ----------------
__global__ __launch_bounds__(256) void k_gximg(char* wsb) {
    __shared__ __align__(16) char smem[65536];
    const int cid = blockIdx.x, tid = threadIdx.x;
    const int l = tid & 63, w = tid >> 6, g = l >> 4, n = l & 15;
    f32x4 acc[4];
    #pragma unroll
    for (int i = 0; i < 4; ++i) acc[i] = (f32x4){0.f, 0.f, 0.f, 0.f};
    gemm_core<8>(wsb + OFF_W1 + (size_t)cid * 524288,
                 wsb + OFF_X1, wsb + OFF_X1, 0, 8, smem, tid, acc);
    const float* bs = (const float*)(wsb + OFF_BS);
    float* gx = (float*)(wsb + OFF_GX) + cid * 4096;
    #pragma unroll
    for (int bg = 0; bg < 4; ++bg)
        #pragma unroll
        for (int p = 0; p < 4; ++p)
            gx[(w * 16 + g * 4 + p) * 64 + bg * 16 + n] =
                acc[bg][p] + bs[w * 1024 + cid * 16 + g * 4 + p];
}

// ---------------- cell gates GEMM, split-K x8 ----------------
template <int KQT>
__global__ __launch_bounds__(256) void k_cellg(const char* __restrict__ Wbase,
                                               size_t Wskip,
                                               const char* __restrict__ A0,
                                               const char* __restrict__ A1,
                                               int HALF, float* __restrict__ P) {
    __shared__ __align__(16) char smem[65536];
    const int tid = threadIdx.x;
    const int rt = blockIdx.x & 63, kq = blockIdx.x >> 6;   // kq 0..7
    const char* Wsrc = Wbase + (size_t)rt * 524288 + Wskip + (size_t)kq * KQT * 16384;
    f32x4 acc[4];
    #pragma unroll
    for (int i = 0; i < 4; ++i) acc[i] = (f32x4){0.f, 0.f, 0.f, 0.f};
    gemm_core<KQT>(Wsrc, A0, A1, kq * KQT, HALF, smem, tid, acc);
    const int l = tid & 63, w = tid >> 6, g = l >> 4, n = l & 15;
    float* Pd = P + kq * 262144 + rt * 4096;
    #pragma unroll
    for (int bg = 0; bg < 4; ++bg)
        #pragma unroll
        for (int p = 0; p < 4; ++p)
            Pd[(w * 16 + g * 4 + p) * 64 + bg * 16 + n] = acc[bg][p];
}

// ---------------- activation: sum 8 partials, LSTM update, write H swz -------
__global__ void k_act(const float* __restrict__ P, const float* __restrict__ bs,
                      const float* __restrict__ gx,
                      float* __restrict__ c, char* __restrict__ Hdst) {
    int rt = blockIdx.x, bq = blockIdx.y;
    int jl = threadIdx.x >> 4, bl = threadIdx.x & 15;
    int b = bq * 16 + bl;
    int base = rt * 4096;
    float g4[4];
    #pragma unroll
    for (int gg = 0; gg < 4; ++gg) {
        float v = 0.f;
        #pragma unroll
        for (int kq = 0; kq < 8; ++kq)
            v += P[kq * 262144 + base + (gg * 16 + jl) * 64 + b];
        g4[gg] = v + (gx ? gx[rt * 4096 + gg * 1024 + jl * 64 + b]
                         : bs[gg * 1024 + rt * 16 + jl]);
    }
    float si = 1.f / (1.f + expf(-g4[0]));
    float sf = 1.f / (1.f + expf(-g4[1]));
    float so = 1.f / (1.f + expf(-g4[3]));
    float tg = tanhf(g4[2]);
    int j = rt * 16 + jl;
    int ci = b * 1024 + j;
    float cn = sf * c[ci] + si * tg;
    c[ci] = cn;
    float hn = so * tanhf(cn);
    unsigned short hi = bf_hi(hn);
    unsigned short lo = bf_hi(hn - bf_f(hi));
    int kt = j >> 6, kl = j & 63;
    int s = kl >> 5, gq = (kl >> 3) & 3, off = kl & 7;
    int chunk = s * 256 + (b >> 4) * 64 + gq * 16 + (b & 15);
    char* d = Hdst + kt * 16384 + chunk * 16 + off * 2;
    *(unsigned short*)d = hi;
    *(unsigned short*)(d + 8192) = lo;
}

// ------- logits GEMM + nt raw store + softmax partials ----------------------
__global__ __launch_bounds__(256) void k_logits(
    const char* __restrict__ WObase, const float* __restrict__ bout,
    const char* __restrict__ A, float* __restrict__ out, int tstep,
    float* __restrict__ pm, float* __restrict__ ps, int* __restrict__ pa) {
    __shared__ __align__(16) char smem[65536];
    const int tid = threadIdx.x;
    const int v0 = blockIdx.x * 64;
    const char* Wsrc = WObase + (size_t)blockIdx.x * 262144;
    f32x4 acc[4];
    #pragma unroll
    for (int i = 0; i < 4; ++i) acc[i] = (f32x4){0.f, 0.f, 0.f, 0.f};
    gemm_core<16>(Wsrc, A, A, 0, 16, smem, tid, acc);
    const int l = tid & 63, w = tid >> 6, g = l >> 4, n = l & 15;
    int bidx = v0 + w * 16 + g * 4; if (bidx > VV - 4) bidx = VV - 4;
    f32x4 bb4 = *(const f32x4*)&bout[bidx];
    float* gl = (float*)smem;   // [64 b][68]
    #pragma unroll
    for (int bg = 0; bg < 4; ++bg)
        #pragma unroll
        for (int p = 0; p < 4; ++p)
            gl[(bg * 16 + n) * 68 + w * 16 + g * 4 + p] = acc[bg][p] + bb4[p];
    __syncthreads();
    int b = tid >> 2, vq = tid & 3;
    float m = -INFINITY, ssum = 0.f; int am = VV;
    if (v0 + vq * 16 < VV) {
        size_t ob = ((size_t)b * TT + tstep) * VV + v0 + vq * 16;
        #pragma unroll
        for (int e4 = 0; e4 < 4; ++e4) {
            f32x4 vv = *(const f32x4*)&gl[b * 68 + vq * 16 + e4 * 4];
            __builtin_nontemporal_store(vv, (f32x4*)&out[ob + e4 * 4]);
            #pragma unroll
            for (int p = 0; p < 4; ++p)
                merge3(m, ssum, am, vv[p], 1.f, v0 + vq * 16 + e4 * 4 + p);
        }
    }
    #pragma unroll
    for (int off = 1; off < 4; off <<= 1) {
        float m2 = __shfl_xor(m, off, 64);
        float s2 = __shfl_xor(ssum, off, 64);
        int a2 = __shfl_xor(am, off, 64);
        merge3(m, ssum, am, m2, s2, a2);
    }
    if (vq == 0) {
        pm[b * PSTRIDE + blockIdx.x] = m;
        ps[b * PSTRIDE + blockIdx.x] = ssum;
        pa[b * PSTRIDE + blockIdx.x] = am;
    }
}

// ---------------- reduce + argmax + fused embedding gather ----------------
__global__ void k_reduce(const float* __restrict__ pm, const float* __restrict__ ps,
                         const int* __restrict__ pa, float* __restrict__ lse_all,
                         int t, const float* __restrict__ Wemb, char* __restrict__ X1) {
    int b = blockIdx.x;
    int tid = threadIdx.x;   // 256
    float m = -INFINITY, s = 0.f; int a = VV;
    for (int i = tid; i < NBT; i += 256)
        merge3(m, s, a, pm[(size_t)b * PSTRIDE + i], ps[(size_t)b * PSTRIDE + i],
               pa[(size_t)b * PSTRIDE + i]);
    #pragma unroll
    for (int off = 1; off < 64; off <<= 1) {
        float m2 = __shfl_xor(m, off, 64);
        float s2 = __shfl_xor(s, off, 64);
        int   a2 = __shfl_xor(a, off, 64);
        merge3(m, s, a, m2, s2, a2);
    }
    __shared__ float sm[4], ss[4]; __shared__ int sa[4]; __shared__ int stok;
    if ((tid & 63) == 0) { sm[tid >> 6] = m; ss[tid >> 6] = s; sa[tid >> 6] = a; }
    __syncthreads();
    if (tid == 0) {
        for (int w = 1; w < 4; ++w) merge3(m, s, a, sm[w], ss[w], sa[w]);
        lse_all[t * 64 + b] = m + logf(s);
        stok = a;
    }
    __syncthreads();
    emb_write(X1, Wemb, stok, b, tid);
}

// ---------------- final pass: row0 one-hot + lse subtract (nt, vectorized) ---
__global__ void k_fix(float* __restrict__ out, const float* __restrict__ lse_all) {
    int v4 = blockIdx.x * 256 + threadIdx.x;   // f32x4 index
    int t = blockIdx.y, b = blockIdx.z;
    if (v4 >= 7500) return;
    size_t o = ((size_t)b * TT + t) * VV + (size_t)v4 * 4;
    f32x4 vv;
    if (t == 0) {
        vv = (f32x4){0.f, 0.f, 0.f, 0.f};
        if (v4 == 0) vv[1] = 1.f;
    } else {
        vv = __builtin_nontemporal_load((const f32x4*)&out[o]);
        float lz = lse_all[t * 64 + b];
        vv[0] -= lz; vv[1] -= lz; vv[2] -= lz; vv[3] -= lz;
    }
    __builtin_nontemporal_store(vv, (f32x4*)&out[o]);
}

extern "C" void kernel_launch(void* const* d_in, const int* in_sizes, int n_in,
                              void* d_out, int out_size, void* d_ws, size_t ws_size,
                              hipStream_t stream) {
    const float* img   = (const float*)d_in[0];
    const float* Wemb  = (const float*)d_in[1];
    const float* Wih1  = (const float*)d_in[2];
    const float* Whh1  = (const float*)d_in[3];
    const float* bih1  = (const float*)d_in[4];
    const float* bhh1  = (const float*)d_in[5];
    const float* Wih2  = (const float*)d_in[6];
    const float* Whh2  = (const float*)d_in[7];
    const float* bih2  = (const float*)d_in[8];
    const float* bhh2  = (const float*)d_in[9];
    const float* Wout  = (const float*)d_in[10];
    const float* bout  = (const float*)d_in[11];
    float* out = (float*)d_out;
    char*  wsb = (char*)d_ws;

    char* W1 = wsb + OFF_W1;
    char* W2 = wsb + OFF_W2;
    char* WO = wsb + OFF_WO;
    char* X1 = wsb + OFF_X1;
    float* c1 = (float*)(wsb + OFF_C1);
    float* c2 = (float*)(wsb + OFF_C2);
    float* P  = (float*)(wsb + OFF_P);
    float* pm = (float*)(wsb + OFF_PM);
    float* ps = (float*)(wsb + OFF_PS);
    int*   pa = (int*)(wsb + OFF_PA);
    float* lse_all = (float*)(wsb + OFF_LSE);
    float* bs = (float*)(wsb + OFF_BS);
    float* gx = (float*)(wsb + OFF_GX);
    auto Hb = [&](size_t base, int bank) { return wsb + base + (size_t)bank * 262144; };

    k_conv_cell<<<dim3(4096, 2), 256, 0, stream>>>(Wih1, Whh1, Wih2, Whh2, wsb);
    k_conv_out<<<15008, 256, 0, stream>>>(Wout, wsb);
    k_conv_img<<<16, 256, 0, stream>>>(img, wsb);
    k_prep<<<1184, 256, 0, stream>>>(wsb, bih1, bhh1, bih2, bhh2);
    k_gximg<<<64, 256, 0, stream>>>(wsb);

    int cur = 0;
    // pre-step: cell1 over K=1536 (emb kts of X1 then 16 H1 kts); img in GX1.
    k_cellg<3><<<512, 256, 0, stream>>>(W1, 131072, X1 + 131072, Hb(OFF_H1, cur),
                                        8, P);
    k_emb0<<<64, 256, 0, stream>>>(Wemb, wsb);   // emb(START) for step t=1
    k_act<<<dim3(64, 4), 256, 0, stream>>>(P, bs, gx, c1, Hb(OFF_H1, cur ^ 1));
    k_cellg<4><<<512, 256, 0, stream>>>(W2, 0, Hb(OFF_H1, cur ^ 1), Hb(OFF_H2, cur),
                                        16, P);
    k_act<<<dim3(64, 4), 256, 0, stream>>>(P, bs + 4096, nullptr, c2,
                                           Hb(OFF_H2, cur ^ 1));
    cur = 1;

    for (int t = 1; t < TT; ++t) {
        k_cellg<3><<<512, 256, 0, stream>>>(W1, 131072, X1 + 131072, Hb(OFF_H1, cur),
                                            8, P);
        k_act<<<dim3(64, 4), 256, 0, stream>>>(P, bs, gx, c1, Hb(OFF_H1, cur ^ 1));
        k_cellg<4><<<512, 256, 0, stream>>>(W2, 0, Hb(OFF_H1, cur ^ 1),
                                            Hb(OFF_H2, cur), 16, P);
        k_act<<<dim3(64, 4), 256, 0, stream>>>(P, bs + 4096, nullptr, c2,
                                               Hb(OFF_H2, cur ^ 1));
        k_logits<<<NBT, 256, 0, stream>>>(WO, bout, Hb(OFF_H2, cur ^ 1),
                                          out, t, pm, ps, pa);
        k_reduce<<<64, 256, 0, stream>>>(pm, ps, pa, lse_all, t, Wemb, X1);
        cur ^= 1;
    }
    k_fix<<<dim3(30, TT, BB), 256, 0, stream>>>(out, lse_all);
}

// Round 15
// 1203.809 us; speedup vs baseline: 1.1170x; 1.1170x over previous
//
#include <hip/hip_runtime.h>
#include <math.h>

#define BB 64
#define EE 512
#define HH 1024
#define VV 30000
#define TT 20
#define NBT 469
#define PSTRIDE 512

typedef __attribute__((ext_vector_type(8))) short bf16x8;
typedef __attribute__((ext_vector_type(4))) float f32x4;

// ---- ws byte offsets ----
#define OFF_W1  ((size_t)0)
#define OFF_W2  ((size_t)33554432)
#define OFF_WO  ((size_t)67108864)
#define OFF_X1  ((size_t)190054400)
#define OFF_H1  ((size_t)190316544)   // + bank*262144
#define OFF_H2  ((size_t)190840832)   // + bank*262144
#define OFF_C1  ((size_t)191365120)
#define OFF_C2  ((size_t)191627264)
#define OFF_P   ((size_t)191889408)   // 8 MB: [kq 0..7][4096][64] f32
#define OFF_PM  ((size_t)200278016)
#define OFF_PS  ((size_t)200409088)
#define OFF_PA  ((size_t)200540160)
#define OFF_LSE ((size_t)200671232)   // [20][64] f32
#define OFF_BS  ((size_t)200676352)   // 8192 f32
#define OFF_GX  ((size_t)200709120)   // 64*4096 f32 = 1MB

__device__ __forceinline__ unsigned short bf_hi(float x) {
    unsigned u = __float_as_uint(x);
    return (unsigned short)((u + 0x7fffu + ((u >> 16) & 1u)) >> 16);
}
__device__ __forceinline__ float bf_f(unsigned short h) {
    return __uint_as_float(((unsigned)h) << 16);
}
__device__ __forceinline__ void merge3(float& m, float& s, int& a,
                                       float m2, float s2, int a2) {
    if (m2 > m) { s = s * expf(m - m2) + s2; m = m2; a = a2; }
    else if (m2 == m) { s += s2; if (a2 < a) a = a2; }
    else { s += s2 * expf(m2 - m); }
}
__device__ __forceinline__ void gl16(const void* g, void* l) {
    __builtin_amdgcn_global_load_lds(
        (const unsigned int __attribute__((address_space(1)))*)g,
        (unsigned int __attribute__((address_space(3)))*)l, 16, 0, 0);
}
__device__ __forceinline__ void cvt8(const float* src, uint4& hv, uint4& lv) {
    unsigned h[8], q[8];
    #pragma unroll
    for (int i = 0; i < 8; ++i) {
        float x = src[i];
        unsigned short hi = bf_hi(x);
        unsigned short lo = bf_hi(x - bf_f(hi));
        h[i] = hi; q[i] = lo;
    }
    hv.x = h[0] | (h[1] << 16); hv.y = h[2] | (h[3] << 16);
    hv.z = h[4] | (h[5] << 16); hv.w = h[6] | (h[7] << 16);
    lv.x = q[0] | (q[1] << 16); lv.y = q[2] | (q[3] << 16);
    lv.z = q[4] | (q[5] << 16); lv.w = q[6] | (q[7] << 16);
}

// ---------------- one-time weight conversion into chunk layout ----------------
__global__ __launch_bounds__(256) void k_conv_cell(
    const float* __restrict__ Wih1, const float* __restrict__ Whh1,
    const float* __restrict__ Wih2, const float* __restrict__ Whh2, char* wsb) {
    int cell = blockIdx.y;
    const float* Wih = cell ? Wih2 : Wih1;
    const float* Whh = cell ? Whh2 : Whh1;
    char* dst = wsb + (cell ? OFF_W2 : OFF_W1);
    unsigned flat = blockIdx.x * 256 + threadIdx.x;  // < 64*32*512
    unsigned c = flat & 511, kt = (flat >> 9) & 31, rt = flat >> 14;
    unsigned s = c >> 8, bg = (c >> 6) & 3, g = (c >> 4) & 3, n = c & 15;
    unsigned row = bg * 1024 + rt * 16 + n;
    unsigned col = (kt & 15) * 64 + s * 32 + g * 8;
    const float* src = (kt < 16 ? Wih : Whh) + (size_t)row * 1024 + col;
    uint4 hv, lv; cvt8(src, hv, lv);
    char* d = dst + (size_t)rt * 524288 + kt * 16384 + c * 16;
    *(uint4*)d = hv;
    *(uint4*)(d + 8192) = lv;
}

__global__ __launch_bounds__(256) void k_conv_out(const float* __restrict__ Wout,
                                                  char* wsb) {
    unsigned flat = blockIdx.x * 256 + threadIdx.x;  // < 469*16*512
    unsigned c = flat & 511, kt = (flat >> 9) & 15, rt = flat >> 13;
    unsigned s = c >> 8, bg = (c >> 6) & 3, g = (c >> 4) & 3, n = c & 15;
    unsigned row = rt * 64 + bg * 16 + n; if (row > VV - 1) row = VV - 1;
    unsigned col = kt * 64 + s * 32 + g * 8;
    const float* src = Wout + (size_t)row * 1024 + col;
    uint4 hv, lv; cvt8(src, hv, lv);
    char* d = wsb + OFF_WO + (size_t)rt * 262144 + kt * 16384 + c * 16;
    *(uint4*)d = hv;
    *(uint4*)(d + 8192) = lv;
}

__global__ __launch_bounds__(256) void k_conv_img(const float* __restrict__ img,
                                                  char* wsb) {
    unsigned flat = blockIdx.x * 256 + threadIdx.x;  // < 8*512
    unsigned c = flat & 511, kt = flat >> 9;
    unsigned s = c >> 8, bg = (c >> 6) & 3, g = (c >> 4) & 3, n = c & 15;
    unsigned b = bg * 16 + n;
    unsigned col = kt * 64 + s * 32 + g * 8;
    const float* src = img + (size_t)b * 512 + col;
    uint4 hv, lv; cvt8(src, hv, lv);
    char* d = wsb + OFF_X1 + kt * 16384 + c * 16;
    *(uint4*)d = hv;
    *(uint4*)(d + 8192) = lv;
}

// ---------------- prep: zeros + bias sums ----------------
__global__ void k_prep(char* wsb,
                       const float* __restrict__ bih1, const float* __restrict__ bhh1,
                       const float* __restrict__ bih2, const float* __restrict__ bhh2) {
    unsigned idx = blockIdx.x * 256 + threadIdx.x;
    if (idx < 131072) { ((unsigned*)(wsb + OFF_C1))[idx] = 0u; return; }   // c1,c2
    idx -= 131072;
    if (idx < 65536) { ((unsigned*)(wsb + OFF_H1))[idx] = 0u; return; }    // H1 bank0
    idx -= 65536;
    if (idx < 65536) { ((unsigned*)(wsb + OFF_H2))[idx] = 0u; return; }    // H2 bank0
    idx -= 65536;
    if (idx < 32768) { ((unsigned*)(wsb + OFF_X1 + 131072))[idx] = 0u; return; } // X1 emb
    idx -= 32768;
    if (idx < 8192) {
        float v = (idx < 4096) ? bih1[idx] + bhh1[idx]
                               : bih2[idx - 4096] + bhh2[idx - 4096];
        ((float*)(wsb + OFF_BS))[idx] = v;
    }
}

// ---------------- emb writer ----------------
__device__ __forceinline__ void emb_write(char* X1, const float* Wemb, int tk,
                                          int b, int tid) {
    #pragma unroll
    for (int i = 0; i < 2; ++i) {
        int e = tid + i * 256;
        float x = Wemb[(size_t)tk * 512 + e];
        unsigned short hi = bf_hi(x);
        unsigned short lo = bf_hi(x - bf_f(hi));
        int k = 512 + e;
        int kt = k >> 6, kl = k & 63;
        int s = kl >> 5, gq = (kl >> 3) & 3, off = kl & 7;
        int chunk = s * 256 + (b >> 4) * 64 + gq * 16 + (b & 15);
        char* d = X1 + kt * 16384 + chunk * 16 + off * 2;
        *(unsigned short*)d = hi;
        *(unsigned short*)(d + 8192) = lo;
    }
}

__global__ void k_emb0(const float* __restrict__ Wemb, char* wsb) {
    emb_write(wsb + OFF_X1, Wemb, 1, blockIdx.x, threadIdx.x);  // START=1
}

// ------- gemm core: 64 rows x 64 b; NKT k-tiles of 64 (2x32KB LDS dbuf) -----
// A source for k-tile kt: global index ta = ktbase+kt; ta<HALF -> A0 else A1.
template <int NKT>
__device__ __forceinline__ void gemm_core(const char* __restrict__ Wsrc,
                                          const char* __restrict__ A0,
                                          const char* __restrict__ A1,
                                          int ktbase, int HALF,
                                          char* smem, int tid, f32x4 acc[4]) {
    const int l = tid & 63, w = tid >> 6, g = l >> 4, n = l & 15;
    auto stage = [&](int kt, char* buf) {
        const char* wsp = Wsrc + kt * 16384;
        int ta = ktbase + kt;
        const char* asp = (ta < HALF) ? (A0 + ta * 16384)
                                      : (A1 + (ta - HALF) * 16384);
        int o = tid * 16;
        gl16(wsp + o, buf + o);
        gl16(wsp + 4096 + o, buf + 4096 + o);
        gl16(wsp + 8192 + o, buf + 8192 + o);
        gl16(wsp + 12288 + o, buf + 12288 + o);
        gl16(asp + o, buf + 16384 + o);
        gl16(asp + 4096 + o, buf + 20480 + o);
        gl16(asp + 8192 + o, buf + 24576 + o);
        gl16(asp + 12288 + o, buf + 28672 + o);
    };
    stage(0, smem);
    __syncthreads();
    for (int kt = 0; kt < NKT; ++kt) {
        char* buf = smem + (kt & 1) * 32768;
        if (kt + 1 < NKT) stage(kt + 1, smem + ((kt + 1) & 1) * 32768);
        #pragma unroll
        for (int s = 0; s < 2; ++s) {
            int wc = (s * 256 + w * 64 + g * 16 + n) * 16;
            bf16x8 ah = *(const bf16x8*)(buf + wc);
            bf16x8 al = *(const bf16x8*)(buf + 8192 + wc);
            #pragma unroll
            for (int bg = 0; bg < 4; ++bg) {
                int ac = (s * 256 + bg * 64 + g * 16 + n) * 16;
                bf16x8 bh = *(const bf16x8*)(buf + 16384 + ac);
                bf16x8 bl = *(const bf16x8*)(buf + 24576 + ac);
                acc[bg] = __builtin_amdgcn_mfma_f32_16x16x32_bf16(ah, bh, acc[bg], 0, 0, 0);
                acc[bg] = __builtin_amdgcn_mfma_f32_16x16x32_bf16(ah, bl, acc[bg], 0, 0, 0);
                acc[bg] = __builtin_amdgcn_mfma_f32_16x16x32_bf16(al, bh, acc[bg], 0, 0, 0);
            }
        }
        __syncthreads();
    }
}

// ---------------- GX1 = Wih1[:, :512] @ img^T + bias1 (once) ----------------
__global__ __launch_bounds__(256) void k_gximg(char* wsb) {
    __shared__ __align__(16) char smem[65536];
    const int cid = blockIdx.x, tid = threadIdx.x;
    const int l = tid & 63, w = tid >> 6, g = l >> 4, n = l & 15;
    f32x4 acc[4];
    #pragma unroll
    for (int i = 0; i < 4; ++i) acc[i] = (f32x4){0.f, 0.f, 0.f, 0.f};
    gemm_core<8>(wsb + OFF_W1 + (size_t)cid * 524288,
                 wsb + OFF_X1, wsb + OFF_X1, 0, 8, smem, tid, acc);
    const float* bs = (const float*)(wsb + OFF_BS);
    float* gx = (float*)(wsb + OFF_GX) + cid * 4096;
    #pragma unroll
    for (int bg = 0; bg < 4; ++bg)
        #pragma unroll
        for (int p = 0; p < 4; ++p)
            gx[(w * 16 + g * 4 + p) * 64 + bg * 16 + n] =
                acc[bg][p] + bs[w * 1024 + cid * 16 + g * 4 + p];
}

// ---------------- cell gates GEMM, split-K x8 ----------------
template <int KQT>
__global__ __launch_bounds__(256) void k_cellg(const char* __restrict__ Wbase,
                                               size_t Wskip,
                                               const char* __restrict__ A0,
                                               const char* __restrict__ A1,
                                               int HALF, float* __restrict__ P) {
    __shared__ __align__(16) char smem[65536];
    const int tid = threadIdx.x;
    const int rt = blockIdx.x & 63, kq = blockIdx.x >> 6;   // kq 0..7
    const char* Wsrc = Wbase + (size_t)rt * 524288 + Wskip + (size_t)kq * KQT * 16384;
    f32x4 acc[4];
    #pragma unroll
    for (int i = 0; i < 4; ++i) acc[i] = (f32x4){0.f, 0.f, 0.f, 0.f};
    gemm_core<KQT>(Wsrc, A0, A1, kq * KQT, HALF, smem, tid, acc);
    const int l = tid & 63, w = tid >> 6, g = l >> 4, n = l & 15;
    float* Pd = P + kq * 262144 + rt * 4096;
    #pragma unroll
    for (int bg = 0; bg < 4; ++bg)
        #pragma unroll
        for (int p = 0; p < 4; ++p)
            Pd[(w * 16 + g * 4 + p) * 64 + bg * 16 + n] = acc[bg][p];
}

// ---------------- activation: sum 8 partials, LSTM update, write H swz -------
__global__ void k_act(const float* __restrict__ P, const float* __restrict__ bs,
                      const float* __restrict__ gx,
                      float* __restrict__ c, char* __restrict__ Hdst) {
    int rt = blockIdx.x, bq = blockIdx.y;
    int jl = threadIdx.x >> 4, bl = threadIdx.x & 15;
    int b = bq * 16 + bl;
    int base = rt * 4096;
    float g4[4];
    #pragma unroll
    for (int gg = 0; gg < 4; ++gg) {
        float v = 0.f;
        #pragma unroll
        for (int kq = 0; kq < 8; ++kq)
            v += P[kq * 262144 + base + (gg * 16 + jl) * 64 + b];
        g4[gg] = v + (gx ? gx[rt * 4096 + gg * 1024 + jl * 64 + b]
                         : bs[gg * 1024 + rt * 16 + jl]);
    }
    float si = 1.f / (1.f + expf(-g4[0]));
    float sf = 1.f / (1.f + expf(-g4[1]));
    float so = 1.f / (1.f + expf(-g4[3]));
    float tg = tanhf(g4[2]);
    int j = rt * 16 + jl;
    int ci = b * 1024 + j;
    float cn = sf * c[ci] + si * tg;
    c[ci] = cn;
    float hn = so * tanhf(cn);
    unsigned short hi = bf_hi(hn);
    unsigned short lo = bf_hi(hn - bf_f(hi));
    int kt = j >> 6, kl = j & 63;
    int s = kl >> 5, gq = (kl >> 3) & 3, off = kl & 7;
    int chunk = s * 256 + (b >> 4) * 64 + gq * 16 + (b & 15);
    char* d = Hdst + kt * 16384 + chunk * 16 + off * 2;
    *(unsigned short*)d = hi;
    *(unsigned short*)(d + 8192) = lo;
}

// -- logits GEMM + raw store + softmax partials + deferred fix of row t-1 ----
__global__ __launch_bounds__(256) void k_logits(
    const char* __restrict__ WObase, const float* __restrict__ bout,
    const char* __restrict__ A, float* __restrict__ out, int tstep,
    float* __restrict__ pm, float* __restrict__ ps, int* __restrict__ pa,
    const float* __restrict__ lse_all) {
    __shared__ __align__(16) char smem[65536];
    const int tid = threadIdx.x;
    const int v0 = blockIdx.x * 64;
    // deferred fix: out[b][t-1][v-slice] -= lse[t-1][b]  (loads overlap staging)
    if (tstep >= 2) {
        int bb = tid >> 2, vq4 = tid & 3;
        if (v0 + vq4 * 16 < VV) {
            float lz = lse_all[(tstep - 1) * 64 + bb];
            size_t ob = ((size_t)bb * TT + (tstep - 1)) * VV + v0 + vq4 * 16;
            #pragma unroll
            for (int e4 = 0; e4 < 4; ++e4) {
                f32x4 vv = *(const f32x4*)&out[ob + e4 * 4];
                vv[0] -= lz; vv[1] -= lz; vv[2] -= lz; vv[3] -= lz;
                *(f32x4*)&out[ob + e4 * 4] = vv;
            }
        }
    }
    const char* Wsrc = WObase + (size_t)blockIdx.x * 262144;
    f32x4 acc[4];
    #pragma unroll
    for (int i = 0; i < 4; ++i) acc[i] = (f32x4){0.f, 0.f, 0.f, 0.f};
    gemm_core<16>(Wsrc, A, A, 0, 16, smem, tid, acc);
    const int l = tid & 63, w = tid >> 6, g = l >> 4, n = l & 15;
    int bidx = v0 + w * 16 + g * 4; if (bidx > VV - 4) bidx = VV - 4;
    f32x4 bb4 = *(const f32x4*)&bout[bidx];
    float* gl = (float*)smem;   // [64 b][68]
    #pragma unroll
    for (int bg = 0; bg < 4; ++bg)
        #pragma unroll
        for (int p = 0; p < 4; ++p)
            gl[(bg * 16 + n) * 68 + w * 16 + g * 4 + p] = acc[bg][p] + bb4[p];
    __syncthreads();
    int b = tid >> 2, vq = tid & 3;
    float m = -INFINITY, ssum = 0.f; int am = VV;
    if (v0 + vq * 16 < VV) {
        size_t ob = ((size_t)b * TT + tstep) * VV + v0 + vq * 16;
        #pragma unroll
        for (int e4 = 0; e4 < 4; ++e4) {
            f32x4 vv = *(const f32x4*)&gl[b * 68 + vq * 16 + e4 * 4];
            *(f32x4*)&out[ob + e4 * 4] = vv;
            #pragma unroll
            for (int p = 0; p < 4; ++p)
                merge3(m, ssum, am, vv[p], 1.f, v0 + vq * 16 + e4 * 4 + p);
        }
    }
    #pragma unroll
    for (int off = 1; off < 4; off <<= 1) {
        float m2 = __shfl_xor(m, off, 64);
        float s2 = __shfl_xor(ssum, off, 64);
        int a2 = __shfl_xor(am, off, 64);
        merge3(m, ssum, am, m2, s2, a2);
    }
    if (vq == 0) {
        pm[b * PSTRIDE + blockIdx.x] = m;
        ps[b * PSTRIDE + blockIdx.x] = ssum;
        pa[b * PSTRIDE + blockIdx.x] = am;
    }
}

// ---------------- reduce + argmax + fused embedding gather ----------------
__global__ void k_reduce(const float* __restrict__ pm, const float* __restrict__ ps,
                         const int* __restrict__ pa, float* __restrict__ lse_all,
                         int t, const float* __restrict__ Wemb, char* __restrict__ X1) {
    int b = blockIdx.x;
    int tid = threadIdx.x;   // 256
    float m = -INFINITY, s = 0.f; int a = VV;
    for (int i = tid; i < NBT; i += 256)
        merge3(m, s, a, pm[(size_t)b * PSTRIDE + i], ps[(size_t)b * PSTRIDE + i],
               pa[(size_t)b * PSTRIDE + i]);
    #pragma unroll
    for (int off = 1; off < 64; off <<= 1) {
        float m2 = __shfl_xor(m, off, 64);
        float s2 = __shfl_xor(s, off, 64);
        int   a2 = __shfl_xor(a, off, 64);
        merge3(m, s, a, m2, s2, a2);
    }
    __shared__ float sm[4], ss[4]; __shared__ int sa[4]; __shared__ int stok;
    if ((tid & 63) == 0) { sm[tid >> 6] = m; ss[tid >> 6] = s; sa[tid >> 6] = a; }
    __syncthreads();
    if (tid == 0) {
        for (int w = 1; w < 4; ++w) merge3(m, s, a, sm[w], ss[w], sa[w]);
        lse_all[t * 64 + b] = m + logf(s);
        stok = a;
    }
    __syncthreads();
    emb_write(X1, Wemb, stok, b, tid);
}

// ------- final pass: t=0 one-hot + t=19 lse subtract (others done inline) ----
__global__ void k_fix(float* __restrict__ out, const float* __restrict__ lse_all) {
    int v4 = blockIdx.x * 256 + threadIdx.x;   // f32x4 index
    int t = blockIdx.y ? (TT - 1) : 0;
    int b = blockIdx.z;
    if (v4 >= 7500) return;
    size_t o = ((size_t)b * TT + t) * VV + (size_t)v4 * 4;
    f32x4 vv;
    if (t == 0) {
        vv = (f32x4){0.f, 0.f, 0.f, 0.f};
        if (v4 == 0) vv[1] = 1.f;
    } else {
        vv = *(const f32x4*)&out[o];
        float lz = lse_all[t * 64 + b];
        vv[0] -= lz; vv[1] -= lz; vv[2] -= lz; vv[3] -= lz;
    }
    *(f32x4*)&out[o] = vv;
}

extern "C" void kernel_launch(void* const* d_in, const int* in_sizes, int n_in,
                              void* d_out, int out_size, void* d_ws, size_t ws_size,
                              hipStream_t stream) {
    const float* img   = (const float*)d_in[0];
    const float* Wemb  = (const float*)d_in[1];
    const float* Wih1  = (const float*)d_in[2];
    const float* Whh1  = (const float*)d_in[3];
    const float* bih1  = (const float*)d_in[4];
    const float* bhh1  = (const float*)d_in[5];
    const float* Wih2  = (const float*)d_in[6];
    const float* Whh2  = (const float*)d_in[7];
    const float* bih2  = (const float*)d_in[8];
    const float* bhh2  = (const float*)d_in[9];
    const float* Wout  = (const float*)d_in[10];
    const float* bout  = (const float*)d_in[11];
    float* out = (float*)d_out;
    char*  wsb = (char*)d_ws;

    char* W1 = wsb + OFF_W1;
    char* W2 = wsb + OFF_W2;
    char* WO = wsb + OFF_WO;
    char* X1 = wsb + OFF_X1;
    float* c1 = (float*)(wsb + OFF_C1);
    float* c2 = (float*)(wsb + OFF_C2);
    float* P  = (float*)(wsb + OFF_P);
    float* pm = (float*)(wsb + OFF_PM);
    float* ps = (float*)(wsb + OFF_PS);
    int*   pa = (int*)(wsb + OFF_PA);
    float* lse_all = (float*)(wsb + OFF_LSE);
    float* bs = (float*)(wsb + OFF_BS);
    float* gx = (float*)(wsb + OFF_GX);
    auto Hb = [&](size_t base, int bank) { return wsb + base + (size_t)bank * 262144; };

    k_conv_cell<<<dim3(4096, 2), 256, 0, stream>>>(Wih1, Whh1, Wih2, Whh2, wsb);
    k_conv_out<<<15008, 256, 0, stream>>>(Wout, wsb);
    k_conv_img<<<16, 256, 0, stream>>>(img, wsb);
    k_prep<<<1184, 256, 0, stream>>>(wsb, bih1, bhh1, bih2, bhh2);
    k_gximg<<<64, 256, 0, stream>>>(wsb);

    int cur = 0;
    // pre-step: cell1 over K=1536 (emb kts of X1 then 16 H1 kts); img in GX1.
    k_cellg<3><<<512, 256, 0, stream>>>(W1, 131072, X1 + 131072, Hb(OFF_H1, cur),
                                        8, P);
    k_emb0<<<64, 256, 0, stream>>>(Wemb, wsb);   // emb(START) for step t=1
    k_act<<<dim3(64, 4), 256, 0, stream>>>(P, bs, gx, c1, Hb(OFF_H1, cur ^ 1));
    k_cellg<4><<<512, 256, 0, stream>>>(W2, 0, Hb(OFF_H1, cur ^ 1), Hb(OFF_H2, cur),
                                        16, P);
    k_act<<<dim3(64, 4), 256, 0, stream>>>(P, bs + 4096, nullptr, c2,
                                           Hb(OFF_H2, cur ^ 1));
    cur = 1;

    for (int t = 1; t < TT; ++t) {
        k_cellg<3><<<512, 256, 0, stream>>>(W1, 131072, X1 + 131072, Hb(OFF_H1, cur),
                                            8, P);
        k_act<<<dim3(64, 4), 256, 0, stream>>>(P, bs, gx, c1, Hb(OFF_H1, cur ^ 1));
        k_cellg<4><<<512, 256, 0, stream>>>(W2, 0, Hb(OFF_H1, cur ^ 1),
                                            Hb(OFF_H2, cur), 16, P);
        k_act<<<dim3(64, 4), 256, 0, stream>>>(P, bs + 4096, nullptr, c2,
                                               Hb(OFF_H2, cur ^ 1));
        k_logits<<<NBT, 256, 0, stream>>>(WO, bout, Hb(OFF_H2, cur ^ 1),
                                          out, t, pm, ps, pa, lse_all);
        k_reduce<<<64, 256, 0, stream>>>(pm, ps, pa, lse_all, t, Wemb, X1);
        cur ^= 1;
    }
    k_fix<<<dim3(30, 2, BB), 256, 0, stream>>>(out, lse_all);
}

// Round 16
// 1182.374 us; speedup vs baseline: 1.1373x; 1.0181x over previous
//
#include <hip/hip_runtime.h>
#include <math.h>

#define BB 64
#define EE 512
#define HH 1024
#define VV 30000
#define TT 20
#define NBT 469
#define PSTRIDE 512

typedef __attribute__((ext_vector_type(8))) short bf16x8;
typedef __attribute__((ext_vector_type(4))) float f32x4;

// ---- ws byte offsets ----
#define OFF_W1  ((size_t)0)
#define OFF_W2  ((size_t)33554432)
#define OFF_WO  ((size_t)67108864)
#define OFF_X1  ((size_t)190054400)
#define OFF_H1  ((size_t)190316544)   // + bank*262144
#define OFF_H2  ((size_t)190840832)   // + bank*262144
#define OFF_C1  ((size_t)191365120)
#define OFF_C2  ((size_t)191627264)
#define OFF_P   ((size_t)191889408)   // 8 MB: [kq 0..7][4096][64] f32
#define OFF_PM  ((size_t)200278016)
#define OFF_PS  ((size_t)200409088)
#define OFF_PA  ((size_t)200540160)
#define OFF_LSE ((size_t)200671232)   // [20][64] f32
#define OFF_BS  ((size_t)200676352)   // 8192 f32
#define OFF_GX  ((size_t)200709120)   // 64*4096 f32 = 1MB

__device__ __forceinline__ unsigned short bf_hi(float x) {
    unsigned u = __float_as_uint(x);
    return (unsigned short)((u + 0x7fffu + ((u >> 16) & 1u)) >> 16);
}
__device__ __forceinline__ float bf_f(unsigned short h) {
    return __uint_as_float(((unsigned)h) << 16);
}
__device__ __forceinline__ void merge3(float& m, float& s, int& a,
                                       float m2, float s2, int a2) {
    if (m2 > m) { s = s * expf(m - m2) + s2; m = m2; a = a2; }
    else if (m2 == m) { s += s2; if (a2 < a) a = a2; }
    else { s += s2 * expf(m2 - m); }
}
__device__ __forceinline__ void gl16(const void* g, void* l) {
    __builtin_amdgcn_global_load_lds(
        (const unsigned int __attribute__((address_space(1)))*)g,
        (unsigned int __attribute__((address_space(3)))*)l, 16, 0, 0);
}
__device__ __forceinline__ void cvt8(const float* src, uint4& hv, uint4& lv) {
    unsigned h[8], q[8];
    #pragma unroll
    for (int i = 0; i < 8; ++i) {
        float x = src[i];
        unsigned short hi = bf_hi(x);
        unsigned short lo = bf_hi(x - bf_f(hi));
        h[i] = hi; q[i] = lo;
    }
    hv.x = h[0] | (h[1] << 16); hv.y = h[2] | (h[3] << 16);
    hv.z = h[4] | (h[5] << 16); hv.w = h[6] | (h[7] << 16);
    lv.x = q[0] | (q[1] << 16); lv.y = q[2] | (q[3] << 16);
    lv.z = q[4] | (q[5] << 16); lv.w = q[6] | (q[7] << 16);
}

// ---------------- one-time weight conversion into chunk layout ----------------
__global__ __launch_bounds__(256) void k_conv_cell(
    const float* __restrict__ Wih1, const float* __restrict__ Whh1,
    const float* __restrict__ Wih2, const float* __restrict__ Whh2, char* wsb) {
    int cell = blockIdx.y;
    const float* Wih = cell ? Wih2 : Wih1;
    const float* Whh = cell ? Whh2 : Whh1;
    char* dst = wsb + (cell ? OFF_W2 : OFF_W1);
    unsigned flat = blockIdx.x * 256 + threadIdx.x;  // < 64*32*512
    unsigned c = flat & 511, kt = (flat >> 9) & 31, rt = flat >> 14;
    unsigned s = c >> 8, bg = (c >> 6) & 3, g = (c >> 4) & 3, n = c & 15;
    unsigned row = bg * 1024 + rt * 16 + n;
    unsigned col = (kt & 15) * 64 + s * 32 + g * 8;
    const float* src = (kt < 16 ? Wih : Whh) + (size_t)row * 1024 + col;
    uint4 hv, lv; cvt8(src, hv, lv);
    char* d = dst + (size_t)rt * 524288 + kt * 16384 + c * 16;
    *(uint4*)d = hv;
    *(uint4*)(d + 8192) = lv;
}

__global__ __launch_bounds__(256) void k_conv_out(const float* __restrict__ Wout,
                                                  char* wsb) {
    unsigned flat = blockIdx.x * 256 + threadIdx.x;  // < 469*16*512
    unsigned c = flat & 511, kt = (flat >> 9) & 15, rt = flat >> 13;
    unsigned s = c >> 8, bg = (c >> 6) & 3, g = (c >> 4) & 3, n = c & 15;
    unsigned row = rt * 64 + bg * 16 + n; if (row > VV - 1) row = VV - 1;
    unsigned col = kt * 64 + s * 32 + g * 8;
    const float* src = Wout + (size_t)row * 1024 + col;
    uint4 hv, lv; cvt8(src, hv, lv);
    char* d = wsb + OFF_WO + (size_t)rt * 262144 + kt * 16384 + c * 16;
    *(uint4*)d = hv;
    *(uint4*)(d + 8192) = lv;
}

__global__ __launch_bounds__(256) void k_conv_img(const float* __restrict__ img,
                                                  char* wsb) {
    unsigned flat = blockIdx.x * 256 + threadIdx.x;  // < 8*512
    unsigned c = flat & 511, kt = flat >> 9;
    unsigned s = c >> 8, bg = (c >> 6) & 3, g = (c >> 4) & 3, n = c & 15;
    unsigned b = bg * 16 + n;
    unsigned col = kt * 64 + s * 32 + g * 8;
    const float* src = img + (size_t)b * 512 + col;
    uint4 hv, lv; cvt8(src, hv, lv);
    char* d = wsb + OFF_X1 + kt * 16384 + c * 16;
    *(uint4*)d = hv;
    *(uint4*)(d + 8192) = lv;
}

// ---------------- prep: zeros + bias sums ----------------
__global__ void k_prep(char* wsb,
                       const float* __restrict__ bih1, const float* __restrict__ bhh1,
                       const float* __restrict__ bih2, const float* __restrict__ bhh2) {
    unsigned idx = blockIdx.x * 256 + threadIdx.x;
    if (idx < 131072) { ((unsigned*)(wsb + OFF_C1))[idx] = 0u; return; }   // c1,c2
    idx -= 131072;
    if (idx < 65536) { ((unsigned*)(wsb + OFF_H1))[idx] = 0u; return; }    // H1 bank0
    idx -= 65536;
    if (idx < 65536) { ((unsigned*)(wsb + OFF_H2))[idx] = 0u; return; }    // H2 bank0
    idx -= 65536;
    if (idx < 32768) { ((unsigned*)(wsb + OFF_X1 + 131072))[idx] = 0u; return; } // X1 emb
    idx -= 32768;
    if (idx < 8192) {
        float v = (idx < 4096) ? bih1[idx] + bhh1[idx]
                               : bih2[idx - 4096] + bhh2[idx - 4096];
        ((float*)(wsb + OFF_BS))[idx] = v;
    }
}

// ---------------- emb writer ----------------
__device__ __forceinline__ void emb_write(char* X1, const float* Wemb, int tk,
                                          int b, int tid) {
    #pragma unroll
    for (int i = 0; i < 2; ++i) {
        int e = tid + i * 256;
        float x = Wemb[(size_t)tk * 512 + e];
        unsigned short hi = bf_hi(x);
        unsigned short lo = bf_hi(x - bf_f(hi));
        int k = 512 + e;
        int kt = k >> 6, kl = k & 63;
        int s = kl >> 5, gq = (kl >> 3) & 3, off = kl & 7;
        int chunk = s * 256 + (b >> 4) * 64 + gq * 16 + (b & 15);
        char* d = X1 + kt * 16384 + chunk * 16 + off * 2;
        *(unsigned short*)d = hi;
        *(unsigned short*)(d + 8192) = lo;
    }
}

__global__ void k_emb0(const float* __restrict__ Wemb, char* wsb) {
    emb_write(wsb + OFF_X1, Wemb, 1, blockIdx.x, threadIdx.x);  // START=1
}

// ------- gemm core: 64 rows x 64 b; NKT k-tiles of 64 (2x32KB LDS dbuf) -----
// A source for k-tile kt: global index ta = ktbase+kt; ta<HALF -> A0 else A1.
template <int NKT>
__device__ __forceinline__ void gemm_core(const char* __restrict__ Wsrc,
                                          const char* __restrict__ A0,
                                          const char* __restrict__ A1,
                                          int ktbase, int HALF,
                                          char* smem, int tid, f32x4 acc[4]) {
    const int l = tid & 63, w = tid >> 6, g = l >> 4, n = l & 15;
    auto stage = [&](int kt, char* buf) {
        const char* wsp = Wsrc + kt * 16384;
        int ta = ktbase + kt;
        const char* asp = (ta < HALF) ? (A0 + ta * 16384)
                                      : (A1 + (ta - HALF) * 16384);
        int o = tid * 16;
        gl16(wsp + o, buf + o);
        gl16(wsp + 4096 + o, buf + 4096 + o);
        gl16(wsp + 8192 + o, buf + 8192 + o);
        gl16(wsp + 12288 + o, buf + 12288 + o);
        gl16(asp + o, buf + 16384 + o);
        gl16(asp + 4096 + o, buf + 20480 + o);
        gl16(asp + 8192 + o, buf + 24576 + o);
        gl16(asp + 12288 + o, buf + 28672 + o);
    };
    stage(0, smem);
    __syncthreads();
    for (int kt = 0; kt < NKT; ++kt) {
        char* buf = smem + (kt & 1) * 32768;
        if (kt + 1 < NKT) stage(kt + 1, smem + ((kt + 1) & 1) * 32768);
        #pragma unroll
        for (int s = 0; s < 2; ++s) {
            int wc = (s * 256 + w * 64 + g * 16 + n) * 16;
            bf16x8 ah = *(const bf16x8*)(buf + wc);
            bf16x8 al = *(const bf16x8*)(buf + 8192 + wc);
            #pragma unroll
            for (int bg = 0; bg < 4; ++bg) {
                int ac = (s * 256 + bg * 64 + g * 16 + n) * 16;
                bf16x8 bh = *(const bf16x8*)(buf + 16384 + ac);
                bf16x8 bl = *(const bf16x8*)(buf + 24576 + ac);
                acc[bg] = __builtin_amdgcn_mfma_f32_16x16x32_bf16(ah, bh, acc[bg], 0, 0, 0);
                acc[bg] = __builtin_amdgcn_mfma_f32_16x16x32_bf16(ah, bl, acc[bg], 0, 0, 0);
                acc[bg] = __builtin_amdgcn_mfma_f32_16x16x32_bf16(al, bh, acc[bg], 0, 0, 0);
            }
        }
        __syncthreads();
    }
}

// ---------------- GX1 = Wih1[:, :512] @ img^T + bias1 (once) ----------------
__global__ __launch_bounds__(256) void k_gximg(char* wsb) {
    __shared__ __align__(16) char smem[65536];
    const int cid = blockIdx.x, tid = threadIdx.x;
    const int l = tid & 63, w = tid >> 6, g = l >> 4, n = l & 15;
    f32x4 acc[4];
    #pragma unroll
    for (int i = 0; i < 4; ++i) acc[i] = (f32x4){0.f, 0.f, 0.f, 0.f};
    gemm_core<8>(wsb + OFF_W1 + (size_t)cid * 524288,
                 wsb + OFF_X1, wsb + OFF_X1, 0, 8, smem, tid, acc);
    const float* bs = (const float*)(wsb + OFF_BS);
    float* gx = (float*)(wsb + OFF_GX) + cid * 4096;
    #pragma unroll
    for (int bg = 0; bg < 4; ++bg)
        #pragma unroll
        for (int p = 0; p < 4; ++p)
            gx[(w * 16 + g * 4 + p) * 64 + bg * 16 + n] =
                acc[bg][p] + bs[w * 1024 + cid * 16 + g * 4 + p];
}

// ---------------- cell gates GEMM, split-K x8 ----------------
template <int KQT>
__global__ __launch_bounds__(256) void k_cellg(const char* __restrict__ Wbase,
                                               size_t Wskip,
                                               const char* __restrict__ A0,
                                               const char* __restrict__ A1,
                                               int HALF, float* __restrict__ P) {
    __shared__ __align__(16) char smem[65536];
    const int tid = threadIdx.x;
    const int rt = blockIdx.x & 63, kq = blockIdx.x >> 6;   // kq 0..7
    const char* Wsrc = Wbase + (size_t)rt * 524288 + Wskip + (size_t)kq * KQT * 16384;
    f32x4 acc[4];
    #pragma unroll
    for (int i = 0; i < 4; ++i) acc[i] = (f32x4){0.f, 0.f, 0.f, 0.f};
    gemm_core<KQT>(Wsrc, A0, A1, kq * KQT, HALF, smem, tid, acc);
    const int l = tid & 63, w = tid >> 6, g = l >> 4, n = l & 15;
    float* Pd = P + kq * 262144 + rt * 4096;
    #pragma unroll
    for (int bg = 0; bg < 4; ++bg)
        #pragma unroll
        for (int p = 0; p < 4; ++p)
            Pd[(w * 16 + g * 4 + p) * 64 + bg * 16 + n] = acc[bg][p];
}

// ---------------- activation: sum 8 partials, LSTM update, write H swz -------
__global__ void k_act(const float* __restrict__ P, const float* __restrict__ bs,
                      const float* __restrict__ gx,
                      float* __restrict__ c, char* __restrict__ Hdst) {
    int rt = blockIdx.x, bq = blockIdx.y;
    int jl = threadIdx.x >> 4, bl = threadIdx.x & 15;
    int b = bq * 16 + bl;
    int base = rt * 4096;
    float g4[4];
    #pragma unroll
    for (int gg = 0; gg < 4; ++gg) {
        float v = 0.f;
        #pragma unroll
        for (int kq = 0; kq < 8; ++kq)
            v += P[kq * 262144 + base + (gg * 16 + jl) * 64 + b];
        g4[gg] = v + (gx ? gx[rt * 4096 + gg * 1024 + jl * 64 + b]
                         : bs[gg * 1024 + rt * 16 + jl]);
    }
    float si = 1.f / (1.f + expf(-g4[0]));
    float sf = 1.f / (1.f + expf(-g4[1]));
    float so = 1.f / (1.f + expf(-g4[3]));
    float tg = tanhf(g4[2]);
    int j = rt * 16 + jl;
    int ci = b * 1024 + j;
    float cn = sf * c[ci] + si * tg;
    c[ci] = cn;
    float hn = so * tanhf(cn);
    unsigned short hi = bf_hi(hn);
    unsigned short lo = bf_hi(hn - bf_f(hi));
    int kt = j >> 6, kl = j & 63;
    int s = kl >> 5, gq = (kl >> 3) & 3, off = kl & 7;
    int chunk = s * 256 + (b >> 4) * 64 + gq * 16 + (b & 15);
    char* d = Hdst + kt * 16384 + chunk * 16 + off * 2;
    *(unsigned short*)d = hi;
    *(unsigned short*)(d + 8192) = lo;
}

// ---------------- logits GEMM + raw store + softmax partials ----------------
__global__ __launch_bounds__(256) void k_logits(
    const char* __restrict__ WObase, const float* __restrict__ bout,
    const char* __restrict__ A, float* __restrict__ out, int tstep,
    float* __restrict__ pm, float* __restrict__ ps, int* __restrict__ pa) {
    __shared__ __align__(16) char smem[65536];
    const int tid = threadIdx.x;
    const int v0 = blockIdx.x * 64;
    const char* Wsrc = WObase + (size_t)blockIdx.x * 262144;
    f32x4 acc[4];
    #pragma unroll
    for (int i = 0; i < 4; ++i) acc[i] = (f32x4){0.f, 0.f, 0.f, 0.f};
    gemm_core<16>(Wsrc, A, A, 0, 16, smem, tid, acc);
    const int l = tid & 63, w = tid >> 6, g = l >> 4, n = l & 15;
    int bidx = v0 + w * 16 + g * 4; if (bidx > VV - 4) bidx = VV - 4;
    f32x4 bb4 = *(const f32x4*)&bout[bidx];
    float* gl = (float*)smem;   // [64 b][68]
    #pragma unroll
    for (int bg = 0; bg < 4; ++bg)
        #pragma unroll
        for (int p = 0; p < 4; ++p)
            gl[(bg * 16 + n) * 68 + w * 16 + g * 4 + p] = acc[bg][p] + bb4[p];
    __syncthreads();
    int b = tid >> 2, vq = tid & 3;
    float m = -INFINITY, ssum = 0.f; int am = VV;
    if (v0 + vq * 16 < VV) {
        size_t ob = ((size_t)b * TT + tstep) * VV + v0 + vq * 16;
        #pragma unroll
        for (int e4 = 0; e4 < 4; ++e4) {
            f32x4 vv = *(const f32x4*)&gl[b * 68 + vq * 16 + e4 * 4];
            *(f32x4*)&out[ob + e4 * 4] = vv;
            #pragma unroll
            for (int p = 0; p < 4; ++p)
                merge3(m, ssum, am, vv[p], 1.f, v0 + vq * 16 + e4 * 4 + p);
        }
    }
    #pragma unroll
    for (int off = 1; off < 4; off <<= 1) {
        float m2 = __shfl_xor(m, off, 64);
        float s2 = __shfl_xor(ssum, off, 64);
        int a2 = __shfl_xor(am, off, 64);
        merge3(m, ssum, am, m2, s2, a2);
    }
    if (vq == 0) {
        pm[b * PSTRIDE + blockIdx.x] = m;
        ps[b * PSTRIDE + blockIdx.x] = ssum;
        pa[b * PSTRIDE + blockIdx.x] = am;
    }
}

// ---------------- reduce + argmax + fused embedding gather ----------------
__global__ void k_reduce(const float* __restrict__ pm, const float* __restrict__ ps,
                         const int* __restrict__ pa, float* __restrict__ lse_all,
                         int t, const float* __restrict__ Wemb, char* __restrict__ X1) {
    int b = blockIdx.x;
    int tid = threadIdx.x;   // 256
    float m = -INFINITY, s = 0.f; int a = VV;
    for (int i = tid; i < NBT; i += 256)
        merge3(m, s, a, pm[(size_t)b * PSTRIDE + i], ps[(size_t)b * PSTRIDE + i],
               pa[(size_t)b * PSTRIDE + i]);
    #pragma unroll
    for (int off = 1; off < 64; off <<= 1) {
        float m2 = __shfl_xor(m, off, 64);
        float s2 = __shfl_xor(s, off, 64);
        int   a2 = __shfl_xor(a, off, 64);
        merge3(m, s, a, m2, s2, a2);
    }
    __shared__ float sm[4], ss[4]; __shared__ int sa[4]; __shared__ int stok;
    if ((tid & 63) == 0) { sm[tid >> 6] = m; ss[tid >> 6] = s; sa[tid >> 6] = a; }
    __syncthreads();
    if (tid == 0) {
        for (int w = 1; w < 4; ++w) merge3(m, s, a, sm[w], ss[w], sa[w]);
        lse_all[t * 64 + b] = m + logf(s);
        stok = a;
    }
    __syncthreads();
    emb_write(X1, Wemb, stok, b, tid);
}

// ---------------- final pass: row0 one-hot + lse subtract (vectorized) -------
__global__ void k_fix(float* __restrict__ out, const float* __restrict__ lse_all) {
    int v4 = blockIdx.x * 256 + threadIdx.x;   // f32x4 index
    int t = blockIdx.y, b = blockIdx.z;
    if (v4 >= 7500) return;
    size_t o = ((size_t)b * TT + t) * VV + (size_t)v4 * 4;
    f32x4 vv;
    if (t == 0) {
        vv = (f32x4){0.f, 0.f, 0.f, 0.f};
        if (v4 == 0) vv[1] = 1.f;
    } else {
        vv = *(const f32x4*)&out[o];
        float lz = lse_all[t * 64 + b];
        vv[0] -= lz; vv[1] -= lz; vv[2] -= lz; vv[3] -= lz;
    }
    *(f32x4*)&out[o] = vv;
}

extern "C" void kernel_launch(void* const* d_in, const int* in_sizes, int n_in,
                              void* d_out, int out_size, void* d_ws, size_t ws_size,
                              hipStream_t stream) {
    const float* img   = (const float*)d_in[0];
    const float* Wemb  = (const float*)d_in[1];
    const float* Wih1  = (const float*)d_in[2];
    const float* Whh1  = (const float*)d_in[3];
    const float* bih1  = (const float*)d_in[4];
    const float* bhh1  = (const float*)d_in[5];
    const float* Wih2  = (const float*)d_in[6];
    const float* Whh2  = (const float*)d_in[7];
    const float* bih2  = (const float*)d_in[8];
    const float* bhh2  = (const float*)d_in[9];
    const float* Wout  = (const float*)d_in[10];
    const float* bout  = (const float*)d_in[11];
    float* out = (float*)d_out;
    char*  wsb = (char*)d_ws;

    char* W1 = wsb + OFF_W1;
    char* W2 = wsb + OFF_W2;
    char* WO = wsb + OFF_WO;
    char* X1 = wsb + OFF_X1;
    float* c1 = (float*)(wsb + OFF_C1);
    float* c2 = (float*)(wsb + OFF_C2);
    float* P  = (float*)(wsb + OFF_P);
    float* pm = (float*)(wsb + OFF_PM);
    float* ps = (float*)(wsb + OFF_PS);
    int*   pa = (int*)(wsb + OFF_PA);
    float* lse_all = (float*)(wsb + OFF_LSE);
    float* bs = (float*)(wsb + OFF_BS);
    float* gx = (float*)(wsb + OFF_GX);
    auto Hb = [&](size_t base, int bank) { return wsb + base + (size_t)bank * 262144; };

    k_conv_cell<<<dim3(4096, 2), 256, 0, stream>>>(Wih1, Whh1, Wih2, Whh2, wsb);
    k_conv_out<<<15008, 256, 0, stream>>>(Wout, wsb);
    k_conv_img<<<16, 256, 0, stream>>>(img, wsb);
    k_prep<<<1184, 256, 0, stream>>>(wsb, bih1, bhh1, bih2, bhh2);
    k_gximg<<<64, 256, 0, stream>>>(wsb);

    int cur = 0;
    // pre-step: cell1 over K=1536 (emb kts of X1 then 16 H1 kts); img in GX1.
    k_cellg<3><<<512, 256, 0, stream>>>(W1, 131072, X1 + 131072, Hb(OFF_H1, cur),
                                        8, P);
    k_emb0<<<64, 256, 0, stream>>>(Wemb, wsb);   // emb(START) for step t=1
    k_act<<<dim3(64, 4), 256, 0, stream>>>(P, bs, gx, c1, Hb(OFF_H1, cur ^ 1));
    k_cellg<4><<<512, 256, 0, stream>>>(W2, 0, Hb(OFF_H1, cur ^ 1), Hb(OFF_H2, cur),
                                        16, P);
    k_act<<<dim3(64, 4), 256, 0, stream>>>(P, bs + 4096, nullptr, c2,
                                           Hb(OFF_H2, cur ^ 1));
    cur = 1;

    for (int t = 1; t < TT; ++t) {
        k_cellg<3><<<512, 256, 0, stream>>>(W1, 131072, X1 + 131072, Hb(OFF_H1, cur),
                                            8, P);
        k_act<<<dim3(64, 4), 256, 0, stream>>>(P, bs, gx, c1, Hb(OFF_H1, cur ^ 1));
        k_cellg<4><<<512, 256, 0, stream>>>(W2, 0, Hb(OFF_H1, cur ^ 1),
                                            Hb(OFF_H2, cur), 16, P);
        k_act<<<dim3(64, 4), 256, 0, stream>>>(P, bs + 4096, nullptr, c2,
                                               Hb(OFF_H2, cur ^ 1));
        k_logits<<<NBT, 256, 0, stream>>>(WO, bout, Hb(OFF_H2, cur ^ 1),
                                          out, t, pm, ps, pa);
        k_reduce<<<64, 256, 0, stream>>>(pm, ps, pa, lse_all, t, Wemb, X1);
        cur ^= 1;
    }
    k_fix<<<dim3(30, TT, BB), 256, 0, stream>>>(out, lse_all);
}